// Round 1
// baseline (2321.920 us; speedup 1.0000x reference)
//
#include <hip/hip_runtime.h>
#include <math.h>

// Problem dims (fixed by reference)
#define BB   64
#define SS   60
#define ENCD 1024
#define ED   512
#define HD   512
#define VD   32000
#define TT   20
#define KT   32   // GEMM k-tile

// ---------------------------------------------------------------------------
// init: zero outputs[:,0,:] and h0/c0
// ---------------------------------------------------------------------------
__global__ __launch_bounds__(256) void init_kernel(float* __restrict__ out,
                                                   float* __restrict__ h,
                                                   float* __restrict__ c) {
  int i = blockIdx.x * 256 + threadIdx.x;
  if (i < BB * VD) {
    int b = i / VD, v = i - b * VD;
    out[(long)b * (TT * VD) + v] = 0.f;
  }
  if (i < BB * HD) { h[i] = 0.f; c[i] = 0.f; }
}

// ---------------------------------------------------------------------------
// Generic NT GEMM: C[z][m][n] = sum_{k in chunk z} A[m][k]*Bw[n][k] (+bias[n])
//   A: row-major [M][lda], Bw: row-major [N][ldb] (dot along rows of both)
//   blockIdx.x = n-tile (64 cols), blockIdx.y = m-tile (64 rows),
//   blockIdx.z = k-chunk (chunk size kChunk, multiple of KT)
//   Cz = C + z*zstride;  Cz[row*ldc + col]
// 256 threads, 4x4 micro-tile per thread, LDS staged transposed [k][m].
// ---------------------------------------------------------------------------
__global__ __launch_bounds__(256) void gemm_nt(
    const float* __restrict__ A, int lda,
    const float* __restrict__ Bw, int ldb,
    const float* __restrict__ bias,
    float* __restrict__ C, long ldc, long zstride,
    int kChunk) {
  __shared__ __align__(16) float As[KT][64];
  __shared__ __align__(16) float Ws[KT][64];
  const int tid = threadIdx.x;
  const int m0 = blockIdx.y * 64, n0 = blockIdx.x * 64;
  const int k0 = blockIdx.z * kChunk, k1 = k0 + kChunk;
  const int tm = tid & 15, tn = tid >> 4;
  const int lr = tid >> 3;          // 0..31
  const int lk = (tid & 7) * 4;     // 0..28
  float acc[4][4] = {};
  for (int kt = k0; kt < k1; kt += KT) {
    __syncthreads();
    #pragma unroll
    for (int p = 0; p < 2; ++p) {
      int m = p * 32 + lr;
      float4 av = *reinterpret_cast<const float4*>(A + (long)(m0 + m) * lda + kt + lk);
      As[lk + 0][m] = av.x; As[lk + 1][m] = av.y;
      As[lk + 2][m] = av.z; As[lk + 3][m] = av.w;
      float4 wv = *reinterpret_cast<const float4*>(Bw + (long)(n0 + m) * ldb + kt + lk);
      Ws[lk + 0][m] = wv.x; Ws[lk + 1][m] = wv.y;
      Ws[lk + 2][m] = wv.z; Ws[lk + 3][m] = wv.w;
    }
    __syncthreads();
    #pragma unroll
    for (int k = 0; k < KT; ++k) {
      float4 a = *reinterpret_cast<const float4*>(&As[k][tm * 4]);
      float4 w = *reinterpret_cast<const float4*>(&Ws[k][tn * 4]);
      acc[0][0] += a.x * w.x; acc[0][1] += a.x * w.y; acc[0][2] += a.x * w.z; acc[0][3] += a.x * w.w;
      acc[1][0] += a.y * w.x; acc[1][1] += a.y * w.y; acc[1][2] += a.y * w.z; acc[1][3] += a.y * w.w;
      acc[2][0] += a.z * w.x; acc[2][1] += a.z * w.y; acc[2][2] += a.z * w.z; acc[2][3] += a.z * w.w;
      acc[3][0] += a.w * w.x; acc[3][1] += a.w * w.y; acc[3][2] += a.w * w.z; acc[3][3] += a.w * w.w;
    }
  }
  float* Cz = C + (long)blockIdx.z * zstride;
  #pragma unroll
  for (int mi = 0; mi < 4; ++mi) {
    int row = m0 + tm * 4 + mi, col = n0 + tn * 4;
    float4 o;
    o.x = acc[mi][0]; o.y = acc[mi][1]; o.z = acc[mi][2]; o.w = acc[mi][3];
    if (bias) {
      o.x += bias[col]; o.y += bias[col + 1]; o.z += bias[col + 2]; o.w += bias[col + 3];
    }
    *reinterpret_cast<float4*>(Cz + (long)row * ldc + col) = o;
  }
}

// ---------------------------------------------------------------------------
// Attention step: scores = proj[b]·h[b]; softmax; attns out; ctx = w·enc[b]
// one block per b, 512 threads (8 waves)
// ---------------------------------------------------------------------------
__global__ __launch_bounds__(512) void attention_step(
    const float* __restrict__ proj, const float* __restrict__ h,
    const float* __restrict__ enc, float* __restrict__ attn_out,
    float* __restrict__ ctx) {
  int b = blockIdx.x;
  __shared__ float sh[HD];
  __shared__ float sc[64];
  __shared__ float sw[64];
  int tid = threadIdx.x;
  sh[tid] = h[b * HD + tid];
  __syncthreads();
  int wave = tid >> 6, lane = tid & 63;
  for (int s = wave; s < SS; s += 8) {
    const float* pr = proj + ((long)b * SS + s) * HD;
    float acc = 0.f;
    #pragma unroll
    for (int k = 0; k < HD / 64; ++k) acc += pr[lane + k * 64] * sh[lane + k * 64];
    #pragma unroll
    for (int off = 32; off; off >>= 1) acc += __shfl_down(acc, off);
    if (lane == 0) sc[s] = acc;
  }
  __syncthreads();
  if (wave == 0) {
    float v = (lane < SS) ? sc[lane] : -INFINITY;
    float m = v;
    #pragma unroll
    for (int off = 32; off; off >>= 1) m = fmaxf(m, __shfl_down(m, off));
    m = __shfl(m, 0);
    float e = (lane < SS) ? __expf(v - m) : 0.f;
    float sum = e;
    #pragma unroll
    for (int off = 32; off; off >>= 1) sum += __shfl_down(sum, off);
    sum = __shfl(sum, 0);
    float w = e / sum;
    if (lane < SS) { sw[lane] = w; attn_out[b * SS + lane] = w; }
  }
  __syncthreads();
  for (int e0 = tid; e0 < ENCD; e0 += 512) {
    float acc = 0.f;
    const float* eb = enc + (long)b * SS * ENCD + e0;
    #pragma unroll
    for (int s = 0; s < SS; ++s) acc += sw[s] * eb[(long)s * ENCD];
    ctx[b * ENCD + e0] = acc;
  }
}

// ---------------------------------------------------------------------------
// Build x[b][0:2048] = [emb_table[word_b], ctx[b], h[b]]
// ---------------------------------------------------------------------------
__global__ __launch_bounds__(256) void build_x(
    const float* __restrict__ emb, const int* __restrict__ caps, int t,
    const float* __restrict__ ctx, const float* __restrict__ h,
    float* __restrict__ x) {
  int b = blockIdx.x;
  int word = caps[b * TT + t];
  const float* er = emb + (long)word * ED;
  for (int k = threadIdx.x; k < ED + ENCD + HD; k += 256) {
    float v;
    if (k < ED) v = er[k];
    else if (k < ED + ENCD) v = ctx[b * ENCD + (k - ED)];
    else v = h[b * HD + (k - ED - ENCD)];
    x[b * 2048 + k] = v;
  }
}

// ---------------------------------------------------------------------------
// LSTM pointwise: reduce 8 split-K partials, add biases, gate math,
// update h,c in place.
// ---------------------------------------------------------------------------
__global__ __launch_bounds__(256) void lstm_pointwise(
    const float* __restrict__ P, const float* __restrict__ b_ih,
    const float* __restrict__ b_hh, float* __restrict__ h,
    float* __restrict__ c) {
  int idx = blockIdx.x * 256 + threadIdx.x;  // 0..32767
  int b = idx >> 9, u = idx & 511;
  float gi = b_ih[u]        + b_hh[u];
  float gf = b_ih[u + 512]  + b_hh[u + 512];
  float gg = b_ih[u + 1024] + b_hh[u + 1024];
  float go = b_ih[u + 1536] + b_hh[u + 1536];
  #pragma unroll
  for (int ks = 0; ks < 8; ++ks) {
    const float* p = P + ((long)ks * BB + b) * 2048;
    gi += p[u]; gf += p[u + 512]; gg += p[u + 1024]; go += p[u + 1536];
  }
  float si = 1.f / (1.f + __expf(-gi));
  float sf = 1.f / (1.f + __expf(-gf));
  float so = 1.f / (1.f + __expf(-go));
  float tg = tanhf(gg);
  float c2 = sf * c[idx] + si * tg;
  float h2 = so * tanhf(c2);
  c[idx] = c2;
  h[idx] = h2;
}

// ---------------------------------------------------------------------------
extern "C" void kernel_launch(void* const* d_in, const int* in_sizes, int n_in,
                              void* d_out_, int out_size, void* d_ws, size_t ws_size,
                              hipStream_t stream) {
  const float* enc   = (const float*)d_in[0];
  const int*   caps  = (const int*)d_in[1];
  const float* emb   = (const float*)d_in[2];
  const float* attnW = (const float*)d_in[3];
  const float* attnB = (const float*)d_in[4];
  const float* W_ih  = (const float*)d_in[5];
  const float* W_hh  = (const float*)d_in[6];
  const float* b_ih  = (const float*)d_in[7];
  const float* b_hh  = (const float*)d_in[8];
  const float* fcW   = (const float*)d_in[9];
  const float* fcb   = (const float*)d_in[10];

  float* out   = (float*)d_out_;                       // [B][T][V]
  float* attns = out + (long)BB * TT * VD;             // [T-1][B][S]

  // workspace layout (floats): ~12.5 MB total
  float* ws   = (float*)d_ws;
  float* proj = ws;                                    // [B*S][H] = 3840*512
  float* h    = proj + (long)BB * SS * HD;             // [B][H]
  float* c    = h + BB * HD;                           // [B][H]
  float* ctx  = c + BB * HD;                           // [B][ENC]
  float* x    = ctx + BB * ENCD;                       // [B][2048]
  float* P    = x + BB * 2048;                         // [8][B][2048] split-K partials

  init_kernel<<<(BB * VD + 255) / 256, 256, 0, stream>>>(out, h, c);

  // proj = enc @ attn_W^T + attn_b : M=3840, N=512, K=1024
  gemm_nt<<<dim3(8, 60, 1), 256, 0, stream>>>(enc, ENCD, attnW, ENCD, attnB,
                                              proj, HD, 0, ENCD);

  for (int t = 0; t < TT - 1; ++t) {
    attention_step<<<BB, 512, 0, stream>>>(proj, h, enc,
                                           attns + (long)t * BB * SS, ctx);
    build_x<<<BB, 256, 0, stream>>>(emb, caps, t, ctx, h, x);
    // gates partials: x[:, :1536] @ W_ih^T  (split-K 6 chunks of 256)
    gemm_nt<<<dim3(32, 1, 6), 256, 0, stream>>>(x, 2048, W_ih, 1536, nullptr,
                                                P, 2048, (long)BB * 2048, 256);
    //                x[:, 1536:] @ W_hh^T  (split-K 2 chunks of 256)
    gemm_nt<<<dim3(32, 1, 2), 256, 0, stream>>>(x + 1536, 2048, W_hh, 512, nullptr,
                                                P + (long)6 * BB * 2048, 2048,
                                                (long)BB * 2048, 256);
    lstm_pointwise<<<128, 256, 0, stream>>>(P, b_ih, b_hh, h, c);
    // out[:, t+1, :] = h @ fc_W^T + fc_b : M=64, N=32000, K=512
    gemm_nt<<<dim3(500, 1, 1), 256, 0, stream>>>(h, HD, fcW, HD, fcb,
                                                 out + (long)(t + 1) * VD,
                                                 (long)TT * VD, 0, HD);
  }
}

// Round 2
// 1709.305 us; speedup vs baseline: 1.3584x; 1.3584x over previous
//
#include <hip/hip_runtime.h>
#include <math.h>

// Problem dims (fixed by reference)
#define BB   64
#define SS   60
#define ENCD 1024
#define ED   512
#define HD   512
#define VD   32000
#define TT   20
#define KT   32   // fp32 GEMM k-tile

typedef unsigned short u16;
typedef __attribute__((ext_vector_type(8))) short short8v;   // 8 bf16 = 4 VGPR
typedef __attribute__((ext_vector_type(4))) float f32x4;

__device__ __forceinline__ u16 f2bf(float x) {   // RNE float->bf16
  unsigned int u = __float_as_uint(x);
  return (u16)((u + 0x7FFFu + ((u >> 16) & 1u)) >> 16);
}

// ---------------------------------------------------------------------------
// init: zero outputs[:,0,:] and h0/c0
// ---------------------------------------------------------------------------
__global__ __launch_bounds__(256) void init_kernel(float* __restrict__ out,
                                                   float* __restrict__ h,
                                                   float* __restrict__ c) {
  int i = blockIdx.x * 256 + threadIdx.x;
  if (i < BB * VD) {
    int b = i / VD, v = i - b * VD;
    out[(long)b * (TT * VD) + v] = 0.f;
  }
  if (i < BB * HD) { h[i] = 0.f; c[i] = 0.f; }
}

// ---------------------------------------------------------------------------
// fp32->bf16 bulk convert (8 elems/thread)
// ---------------------------------------------------------------------------
__global__ __launch_bounds__(256) void convert_bf16_k(const float* __restrict__ src,
                                                      u16* __restrict__ dst, long n) {
  long i = ((long)blockIdx.x * 256 + threadIdx.x) * 8;
  if (i + 8 <= n) {
    float4 a = *reinterpret_cast<const float4*>(src + i);
    float4 b = *reinterpret_cast<const float4*>(src + i + 4);
    uint4 o;
    o.x = (unsigned)f2bf(a.x) | ((unsigned)f2bf(a.y) << 16);
    o.y = (unsigned)f2bf(a.z) | ((unsigned)f2bf(a.w) << 16);
    o.z = (unsigned)f2bf(b.x) | ((unsigned)f2bf(b.y) << 16);
    o.w = (unsigned)f2bf(b.z) | ((unsigned)f2bf(b.w) << 16);
    *reinterpret_cast<uint4*>(dst + i) = o;
  }
}

// ---------------------------------------------------------------------------
// Generic fp32 NT GEMM (kept for proj / gates / fallback)
// ---------------------------------------------------------------------------
__global__ __launch_bounds__(256) void gemm_nt(
    const float* __restrict__ A, int lda,
    const float* __restrict__ Bw, int ldb,
    const float* __restrict__ bias,
    float* __restrict__ C, long ldc, long zstride,
    int kChunk) {
  __shared__ __align__(16) float As[KT][64];
  __shared__ __align__(16) float Ws[KT][64];
  const int tid = threadIdx.x;
  const int m0 = blockIdx.y * 64, n0 = blockIdx.x * 64;
  const int k0 = blockIdx.z * kChunk, k1 = k0 + kChunk;
  const int tm = tid & 15, tn = tid >> 4;
  const int lr = tid >> 3;
  const int lk = (tid & 7) * 4;
  float acc[4][4] = {};
  for (int kt = k0; kt < k1; kt += KT) {
    __syncthreads();
    #pragma unroll
    for (int p = 0; p < 2; ++p) {
      int m = p * 32 + lr;
      float4 av = *reinterpret_cast<const float4*>(A + (long)(m0 + m) * lda + kt + lk);
      As[lk + 0][m] = av.x; As[lk + 1][m] = av.y;
      As[lk + 2][m] = av.z; As[lk + 3][m] = av.w;
      float4 wv = *reinterpret_cast<const float4*>(Bw + (long)(n0 + m) * ldb + kt + lk);
      Ws[lk + 0][m] = wv.x; Ws[lk + 1][m] = wv.y;
      Ws[lk + 2][m] = wv.z; Ws[lk + 3][m] = wv.w;
    }
    __syncthreads();
    #pragma unroll
    for (int k = 0; k < KT; ++k) {
      float4 a = *reinterpret_cast<const float4*>(&As[k][tm * 4]);
      float4 w = *reinterpret_cast<const float4*>(&Ws[k][tn * 4]);
      acc[0][0] += a.x * w.x; acc[0][1] += a.x * w.y; acc[0][2] += a.x * w.z; acc[0][3] += a.x * w.w;
      acc[1][0] += a.y * w.x; acc[1][1] += a.y * w.y; acc[1][2] += a.y * w.z; acc[1][3] += a.y * w.w;
      acc[2][0] += a.z * w.x; acc[2][1] += a.z * w.y; acc[2][2] += a.z * w.z; acc[2][3] += a.z * w.w;
      acc[3][0] += a.w * w.x; acc[3][1] += a.w * w.y; acc[3][2] += a.w * w.z; acc[3][3] += a.w * w.w;
    }
  }
  float* Cz = C + (long)blockIdx.z * zstride;
  #pragma unroll
  for (int mi = 0; mi < 4; ++mi) {
    int row = m0 + tm * 4 + mi, col = n0 + tn * 4;
    float4 o;
    o.x = acc[mi][0]; o.y = acc[mi][1]; o.z = acc[mi][2]; o.w = acc[mi][3];
    if (bias) {
      o.x += bias[col]; o.y += bias[col + 1]; o.z += bias[col + 2]; o.w += bias[col + 3];
    }
    *reinterpret_cast<float4*>(Cz + (long)row * ldc + col) = o;
  }
}

// ---------------------------------------------------------------------------
// fc GEMM, bf16 MFMA: out[b][n] = sum_k hb[b][k]*Wb[n][k] + bias[n]
// M=64 (batch), N tile 64 per block (grid 500), K=512 in 8 chunks of 64.
// LDS linear [64 rows][64 bf16]; XOR swizzle ((row&7)) on 16B slots applied
// to the global SOURCE (global_load_lds writes linearly) and to the ds_read.
// ---------------------------------------------------------------------------
__global__ __launch_bounds__(256) void fc_mfma(
    const u16* __restrict__ hb,        // [64][512] bf16
    const u16* __restrict__ Wb,        // [32000][512] bf16
    const float* __restrict__ bias,
    float* __restrict__ outp) {        // base already offset to column t+1; ldc = TT*VD
  __shared__ __align__(16) u16 Asm[2][64 * 64];
  __shared__ __align__(16) u16 Wsm[2][64 * 64];
  const int tid = threadIdx.x;
  const int n0 = blockIdx.x * 64;
  const int wv = tid >> 6, lane = tid & 63;
  const int srow = tid >> 3;           // staging: rows 0..31 (+32 on 2nd issue)
  const int sslot = tid & 7;           // staging: 16B slot within 128B row

#define STAGE_CH(buf, kc) do {                                                    \
    _Pragma("unroll")                                                             \
    for (int ii = 0; ii < 2; ++ii) {                                              \
      int row_ = ii * 32 + srow;                                                  \
      int col_ = (kc) + ((sslot ^ (row_ & 7)) * 8);                               \
      __builtin_amdgcn_global_load_lds(                                           \
          (const __attribute__((address_space(1))) void*)(hb + row_ * HD + col_), \
          (__attribute__((address_space(3))) void*)((char*)&Asm[0][0] + (buf) * 8192 + ii * 4096 + tid * 16), \
          16, 0, 0);                                                              \
      __builtin_amdgcn_global_load_lds(                                           \
          (const __attribute__((address_space(1))) void*)(Wb + (long)(n0 + row_) * HD + col_), \
          (__attribute__((address_space(3))) void*)((char*)&Wsm[0][0] + (buf) * 8192 + ii * 4096 + tid * 16), \
          16, 0, 0);                                                              \
    }                                                                             \
  } while (0)

  f32x4 acc[4] = {{0.f,0.f,0.f,0.f},{0.f,0.f,0.f,0.f},{0.f,0.f,0.f,0.f},{0.f,0.f,0.f,0.f}};
  const int frow = lane & 15, fgrp = lane >> 4;
  const int wrow = wv * 16 + frow;     // W row within the 64-row tile

  STAGE_CH(0, 0);
  asm volatile("s_waitcnt vmcnt(0)");
  __syncthreads();

  for (int kc = 0; kc < 8; ++kc) {
    const char* Ab = (const char*)&Asm[0][0] + (kc & 1) * 8192;
    const char* Wp = (const char*)&Wsm[0][0] + (kc & 1) * 8192;
    if (kc < 7) STAGE_CH((kc + 1) & 1, (kc + 1) * 64);
    #pragma unroll
    for (int ks = 0; ks < 2; ++ks) {
      int slot = (((ks * 4 + fgrp) ^ (frow & 7)) * 16);
      short8v bfr = *reinterpret_cast<const short8v*>(Wp + wrow * 128 + slot);
      #pragma unroll
      for (int m = 0; m < 4; ++m) {
        short8v afr = *reinterpret_cast<const short8v*>(Ab + (m * 16 + frow) * 128 + slot);
        acc[m] = __builtin_amdgcn_mfma_f32_16x16x32_bf16(afr, bfr, acc[m], 0, 0, 0);
      }
    }
    asm volatile("s_waitcnt vmcnt(0)");
    __syncthreads();
  }

  const int col = n0 + wv * 16 + frow;
  const float bv = bias[col];
  #pragma unroll
  for (int m = 0; m < 4; ++m) {
    #pragma unroll
    for (int r = 0; r < 4; ++r) {
      int row = m * 16 + fgrp * 4 + r;          // C/D: row=(lane>>4)*4+reg (+16 per M-rep)
      outp[(long)row * ((long)TT * VD) + col] = acc[m][r] + bv;
    }
  }
#undef STAGE_CH
}

// ---------------------------------------------------------------------------
// Attention step
// ---------------------------------------------------------------------------
__global__ __launch_bounds__(512) void attention_step(
    const float* __restrict__ proj, const float* __restrict__ h,
    const float* __restrict__ enc, float* __restrict__ attn_out,
    float* __restrict__ ctx) {
  int b = blockIdx.x;
  __shared__ float sh[HD];
  __shared__ float sc[64];
  __shared__ float sw[64];
  int tid = threadIdx.x;
  sh[tid] = h[b * HD + tid];
  __syncthreads();
  int wave = tid >> 6, lane = tid & 63;
  for (int s = wave; s < SS; s += 8) {
    const float* pr = proj + ((long)b * SS + s) * HD;
    float acc = 0.f;
    #pragma unroll
    for (int k = 0; k < HD / 64; ++k) acc += pr[lane + k * 64] * sh[lane + k * 64];
    #pragma unroll
    for (int off = 32; off; off >>= 1) acc += __shfl_down(acc, off);
    if (lane == 0) sc[s] = acc;
  }
  __syncthreads();
  if (wave == 0) {
    float v = (lane < SS) ? sc[lane] : -INFINITY;
    float m = v;
    #pragma unroll
    for (int off = 32; off; off >>= 1) m = fmaxf(m, __shfl_down(m, off));
    m = __shfl(m, 0);
    float e = (lane < SS) ? __expf(v - m) : 0.f;
    float sum = e;
    #pragma unroll
    for (int off = 32; off; off >>= 1) sum += __shfl_down(sum, off);
    sum = __shfl(sum, 0);
    float w = e / sum;
    if (lane < SS) { sw[lane] = w; attn_out[b * SS + lane] = w; }
  }
  __syncthreads();
  for (int e0 = tid; e0 < ENCD; e0 += 512) {
    float acc = 0.f;
    const float* eb = enc + (long)b * SS * ENCD + e0;
    #pragma unroll
    for (int s = 0; s < SS; ++s) acc += sw[s] * eb[(long)s * ENCD];
    ctx[b * ENCD + e0] = acc;
  }
}

// ---------------------------------------------------------------------------
// Build x[b][0:2048] = [emb_table[word_b], ctx[b], h[b]]
// ---------------------------------------------------------------------------
__global__ __launch_bounds__(256) void build_x(
    const float* __restrict__ emb, const int* __restrict__ caps, int t,
    const float* __restrict__ ctx, const float* __restrict__ h,
    float* __restrict__ x) {
  int b = blockIdx.x;
  int word = caps[b * TT + t];
  const float* er = emb + (long)word * ED;
  for (int k = threadIdx.x; k < ED + ENCD + HD; k += 256) {
    float v;
    if (k < ED) v = er[k];
    else if (k < ED + ENCD) v = ctx[b * ENCD + (k - ED)];
    else v = h[b * HD + (k - ED - ENCD)];
    x[b * 2048 + k] = v;
  }
}

// ---------------------------------------------------------------------------
// LSTM pointwise: reduce 8 split-K partials, gate math, update h,c (+ bf16 h)
// ---------------------------------------------------------------------------
__global__ __launch_bounds__(256) void lstm_pointwise(
    const float* __restrict__ P, const float* __restrict__ b_ih,
    const float* __restrict__ b_hh, float* __restrict__ h,
    float* __restrict__ c, u16* __restrict__ hb) {
  int idx = blockIdx.x * 256 + threadIdx.x;  // 0..32767
  int b = idx >> 9, u = idx & 511;
  float gi = b_ih[u]        + b_hh[u];
  float gf = b_ih[u + 512]  + b_hh[u + 512];
  float gg = b_ih[u + 1024] + b_hh[u + 1024];
  float go = b_ih[u + 1536] + b_hh[u + 1536];
  #pragma unroll
  for (int ks = 0; ks < 8; ++ks) {
    const float* p = P + ((long)ks * BB + b) * 2048;
    gi += p[u]; gf += p[u + 512]; gg += p[u + 1024]; go += p[u + 1536];
  }
  float si = 1.f / (1.f + __expf(-gi));
  float sf = 1.f / (1.f + __expf(-gf));
  float so = 1.f / (1.f + __expf(-go));
  float tg = tanhf(gg);
  float c2 = sf * c[idx] + si * tg;
  float h2 = so * tanhf(c2);
  c[idx] = c2;
  h[idx] = h2;
  if (hb) hb[idx] = f2bf(h2);
}

// ---------------------------------------------------------------------------
extern "C" void kernel_launch(void* const* d_in, const int* in_sizes, int n_in,
                              void* d_out_, int out_size, void* d_ws, size_t ws_size,
                              hipStream_t stream) {
  const float* enc   = (const float*)d_in[0];
  const int*   caps  = (const int*)d_in[1];
  const float* emb   = (const float*)d_in[2];
  const float* attnW = (const float*)d_in[3];
  const float* attnB = (const float*)d_in[4];
  const float* W_ih  = (const float*)d_in[5];
  const float* W_hh  = (const float*)d_in[6];
  const float* b_ih  = (const float*)d_in[7];
  const float* b_hh  = (const float*)d_in[8];
  const float* fcW   = (const float*)d_in[9];
  const float* fcb   = (const float*)d_in[10];

  float* out   = (float*)d_out_;                       // [B][T][V]
  float* attns = out + (long)BB * TT * VD;             // [T-1][B][S]

  // workspace layout
  float* ws   = (float*)d_ws;
  float* proj = ws;                                    // [B*S][H]
  float* h    = proj + (long)BB * SS * HD;
  float* c    = h + BB * HD;
  float* ctx  = c + BB * HD;
  float* x    = ctx + BB * ENCD;
  float* P    = x + BB * 2048;                         // [8][B][2048]
  u16*   hbf  = (u16*)(P + (long)8 * BB * 2048);       // [B][H] bf16
  u16*   Wbf  = hbf + (long)BB * HD;                   // [V][H] bf16
  size_t need = (size_t)((char*)(Wbf + (long)VD * HD) - (char*)d_ws);
  const bool use_mfma = (ws_size >= need);

  init_kernel<<<(BB * VD + 255) / 256, 256, 0, stream>>>(out, h, c);

  if (use_mfma) {
    long n = (long)VD * HD;
    convert_bf16_k<<<(int)(n / 2048), 256, 0, stream>>>(fcW, Wbf, n);
  }

  // proj = enc @ attn_W^T + attn_b : M=3840, N=512, K=1024
  gemm_nt<<<dim3(8, 60, 1), 256, 0, stream>>>(enc, ENCD, attnW, ENCD, attnB,
                                              proj, HD, 0, ENCD);

  for (int t = 0; t < TT - 1; ++t) {
    attention_step<<<BB, 512, 0, stream>>>(proj, h, enc,
                                           attns + (long)t * BB * SS, ctx);
    build_x<<<BB, 256, 0, stream>>>(emb, caps, t, ctx, h, x);
    gemm_nt<<<dim3(32, 1, 6), 256, 0, stream>>>(x, 2048, W_ih, 1536, nullptr,
                                                P, 2048, (long)BB * 2048, 256);
    gemm_nt<<<dim3(32, 1, 2), 256, 0, stream>>>(x + 1536, 2048, W_hh, 512, nullptr,
                                                P + (long)6 * BB * 2048, 2048,
                                                (long)BB * 2048, 256);
    lstm_pointwise<<<128, 256, 0, stream>>>(P, b_ih, b_hh, h, c,
                                            use_mfma ? hbf : nullptr);
    if (use_mfma) {
      fc_mfma<<<VD / 64, 256, 0, stream>>>(hbf, Wbf, fcb,
                                           out + (long)(t + 1) * VD);
    } else {
      gemm_nt<<<dim3(500, 1, 1), 256, 0, stream>>>(h, HD, fcW, HD, fcb,
                                                   out + (long)(t + 1) * VD,
                                                   (long)TT * VD, 0, HD);
    }
  }
}